// Round 1
// baseline (2798.541 us; speedup 1.0000x reference)
//
#include <hip/hip_runtime.h>

// RGCN: 3× HeteroGraphConv(mean over R=4 relations of GraphConv(norm='both')).
// Key identity: segment_sum is linear, so aggregate-then-matmul == matmul-then-
// aggregate. Layers 0/1 aggregate first (fuses epilogue into GEMM, no hn buf);
// layer 2 projects 128->16 first (8x less scatter traffic).

#define NNODES 100000
#define NEDGE  400000
#define NREL   4
#define DHID   128
#define NCLS   16

// ---------------- degrees ----------------
__global__ void deg_hist(const int* __restrict__ src, const int* __restrict__ dst,
                         float* __restrict__ rs_out, float* __restrict__ rs_in) {
    int e = blockIdx.x * 256 + threadIdx.x;
    int r = blockIdx.y;
    if (e < NEDGE) {
        int s = src[r * NEDGE + e];
        int d = dst[r * NEDGE + e];
        atomicAdd(&rs_out[r * NNODES + s], 1.0f);
        atomicAdd(&rs_in [r * NNODES + d], 1.0f);
    }
}

__global__ void rsqrt_fin(float* __restrict__ v, int n) {
    int i = blockIdx.x * 256 + threadIdx.x;
    if (i < n) v[i] = rsqrtf(fmaxf(v[i], 1.0f));
}

// ---------------- edge scatter, 128 feats ----------------
// agg[dst] += h[src] * rs_out[src];  2 edges per 256-thread block, coalesced.
__global__ void scatter128(const float* __restrict__ h, const float* __restrict__ rs,
                           const int* __restrict__ src, const int* __restrict__ dst,
                           float* __restrict__ agg) {
    int e = blockIdx.x * 2 + (threadIdx.x >> 7);
    int j = threadIdx.x & 127;
    if (e < NEDGE) {
        int s = src[e], d = dst[e];
        atomicAdd(&agg[d * DHID + j], h[s * DHID + j] * rs[s]);
    }
}

// ---------------- GEMM 128x128 with fused GraphConv epilogue ----------------
// out[row,:] += relu_opt((A[row,:] @ W) * rs_in[row] + bias) * (1/R)
// BM=128, BN=128, BK=32, 256 threads, 8x8 acc/thread.
template <int RELU>
__global__ __launch_bounds__(256) void gemm128_ep(
        const float* __restrict__ A, const float* __restrict__ W,
        const float* __restrict__ bias, const float* __restrict__ rsin,
        float* __restrict__ out) {
    __shared__ float As[128][33];   // +1 pad
    __shared__ float Ws[32][132];   // +4 pad (keeps float4-able rows)
    int tid = threadIdx.x;
    int tx = tid & 15;     // col group: cols tx*8 .. +7
    int ty = tid >> 4;     // row group: rows ty*8 .. +7
    int row0 = blockIdx.x * 128;

    float acc[8][8];
#pragma unroll
    for (int i = 0; i < 8; ++i)
#pragma unroll
        for (int j = 0; j < 8; ++j) acc[i][j] = 0.f;

    for (int kt = 0; kt < 4; ++kt) {
        int k0 = kt * 32;
#pragma unroll
        for (int i = 0; i < 16; ++i) {          // A tile 128x32
            int idx = tid + i * 256;
            int rr = idx >> 5, kk = idx & 31;
            int row = row0 + rr;
            As[rr][kk] = (row < NNODES) ? A[row * DHID + k0 + kk] : 0.f;
        }
#pragma unroll
        for (int i = 0; i < 16; ++i) {          // W tile 32x128
            int idx = tid + i * 256;
            int rr = idx >> 7, cc = idx & 127;
            Ws[rr][cc] = W[(k0 + rr) * DHID + cc];
        }
        __syncthreads();
#pragma unroll
        for (int k = 0; k < 32; ++k) {
            float a[8], w[8];
#pragma unroll
            for (int i = 0; i < 8; ++i) a[i] = As[ty * 8 + i][k];
#pragma unroll
            for (int j = 0; j < 8; ++j) w[j] = Ws[k][tx * 8 + j];
#pragma unroll
            for (int i = 0; i < 8; ++i)
#pragma unroll
                for (int j = 0; j < 8; ++j) acc[i][j] += a[i] * w[j];
        }
        __syncthreads();
    }

#pragma unroll
    for (int i = 0; i < 8; ++i) {
        int row = row0 + ty * 8 + i;
        if (row < NNODES) {
            float rs = rsin[row];
#pragma unroll
            for (int j = 0; j < 8; ++j) {
                int c = tx * 8 + j;
                float v = acc[i][j] * rs + bias[c];
                if (RELU) v = fmaxf(v, 0.f);
                out[row * DHID + c] += v * 0.25f;   // 1/R folded
            }
        }
    }
}

// ---------------- layer 2: hn16 = (H * rs_out) @ W2   [N,128]@[128,16] ----------------
__global__ __launch_bounds__(256) void gemm16_scale(
        const float* __restrict__ H, const float* __restrict__ rsout,
        const float* __restrict__ W, float* __restrict__ hn) {
    __shared__ float As[64][129];
    __shared__ float Ws[128][17];
    int tid = threadIdx.x;
    int col = tid & 15;
    int rg  = tid >> 4;          // rows rg*4 .. +3
    int row0 = blockIdx.x * 64;
#pragma unroll
    for (int i = 0; i < 32; ++i) {   // A tile 64x128, row-scaled at load
        int idx = tid + i * 256;
        int rr = idx >> 7, kk = idx & 127;
        int row = row0 + rr;
        As[rr][kk] = (row < NNODES) ? H[row * DHID + kk] * rsout[row] : 0.f;
    }
#pragma unroll
    for (int i = 0; i < 8; ++i) {    // W 128x16
        int idx = tid + i * 256;
        int rr = idx >> 4, cc = idx & 15;
        Ws[rr][cc] = W[rr * NCLS + cc];
    }
    __syncthreads();
    float acc[4] = {0.f, 0.f, 0.f, 0.f};
    for (int k = 0; k < 128; ++k) {
        float w = Ws[k][col];
#pragma unroll
        for (int i = 0; i < 4; ++i) acc[i] += As[rg * 4 + i][k] * w;
    }
#pragma unroll
    for (int i = 0; i < 4; ++i) {
        int row = row0 + rg * 4 + i;
        if (row < NNODES) hn[row * NCLS + col] = acc[i];
    }
}

__global__ void scatter16(const float* __restrict__ hn, const int* __restrict__ src,
                          const int* __restrict__ dst, float* __restrict__ agg) {
    int e = blockIdx.x * 16 + (threadIdx.x >> 4);
    int j = threadIdx.x & 15;
    if (e < NEDGE) {
        int s = src[e], d = dst[e];
        atomicAdd(&agg[d * NCLS + j], hn[s * NCLS + j]);
    }
}

__global__ void epi16(const float* __restrict__ agg, const float* __restrict__ rsin,
                      const float* __restrict__ b, float* __restrict__ out) {
    int i = blockIdx.x * 256 + threadIdx.x;
    if (i < NNODES * NCLS) {
        int n = i >> 4, c = i & 15;
        out[i] += (agg[i] * rsin[n] + b[c]) * 0.25f;
    }
}

extern "C" void kernel_launch(void* const* d_in, const int* in_sizes, int n_in,
                              void* d_out, int out_size, void* d_ws, size_t ws_size,
                              hipStream_t stream) {
    const float* x  = (const float*)d_in[0];
    const float* W0 = (const float*)d_in[1];
    const float* b0 = (const float*)d_in[2];
    const float* W1 = (const float*)d_in[3];
    const float* b1 = (const float*)d_in[4];
    const float* W2 = (const float*)d_in[5];
    const float* b2 = (const float*)d_in[6];
    const int*   src = (const int*)d_in[7];
    const int*   dst = (const int*)d_in[8];
    float* out = (float*)d_out;

    // workspace layout (floats): rs_out[R*N] rs_in[R*N] h1[N*128] h2[N*128] agg[N*128]
    // layer 2 reuses h1 as hn16 and agg as agg16.  Total ~157 MB.
    float* ws     = (float*)d_ws;
    float* rs_out = ws;
    float* rs_in  = rs_out + (size_t)NREL * NNODES;
    float* h1     = rs_in  + (size_t)NREL * NNODES;
    float* h2     = h1 + (size_t)NNODES * DHID;
    float* agg    = h2 + (size_t)NNODES * DHID;

    // ---- degrees (shared by all layers) ----
    hipMemsetAsync(rs_out, 0, 2ull * NREL * NNODES * sizeof(float), stream);
    dim3 hg((NEDGE + 255) / 256, NREL);
    deg_hist<<<hg, 256, 0, stream>>>(src, dst, rs_out, rs_in);
    rsqrt_fin<<<(2 * NREL * NNODES + 255) / 256, 256, 0, stream>>>(rs_out, 2 * NREL * NNODES);

    int gemm_blocks = (NNODES + 127) / 128;

    // ---- layer 0: x -> h1 (relu) ----
    hipMemsetAsync(h1, 0, (size_t)NNODES * DHID * sizeof(float), stream);
    for (int r = 0; r < NREL; ++r) {
        hipMemsetAsync(agg, 0, (size_t)NNODES * DHID * sizeof(float), stream);
        scatter128<<<NEDGE / 2, 256, 0, stream>>>(x, rs_out + (size_t)r * NNODES,
                                                  src + (size_t)r * NEDGE, dst + (size_t)r * NEDGE, agg);
        gemm128_ep<1><<<gemm_blocks, 256, 0, stream>>>(agg, W0 + (size_t)r * DHID * DHID,
                                                       b0 + (size_t)r * DHID,
                                                       rs_in + (size_t)r * NNODES, h1);
    }

    // ---- layer 1: h1 -> h2 (relu) ----
    hipMemsetAsync(h2, 0, (size_t)NNODES * DHID * sizeof(float), stream);
    for (int r = 0; r < NREL; ++r) {
        hipMemsetAsync(agg, 0, (size_t)NNODES * DHID * sizeof(float), stream);
        scatter128<<<NEDGE / 2, 256, 0, stream>>>(h1, rs_out + (size_t)r * NNODES,
                                                  src + (size_t)r * NEDGE, dst + (size_t)r * NEDGE, agg);
        gemm128_ep<1><<<gemm_blocks, 256, 0, stream>>>(agg, W1 + (size_t)r * DHID * DHID,
                                                       b1 + (size_t)r * DHID,
                                                       rs_in + (size_t)r * NNODES, h2);
    }

    // ---- layer 2: h2 -> out (no act), matmul-first ----
    float* hn16  = h1;   // reuse
    float* agg16 = agg;  // reuse
    hipMemsetAsync(out, 0, (size_t)NNODES * NCLS * sizeof(float), stream);
    for (int r = 0; r < NREL; ++r) {
        gemm16_scale<<<(NNODES + 63) / 64, 256, 0, stream>>>(h2, rs_out + (size_t)r * NNODES,
                                                             W2 + (size_t)r * DHID * NCLS, hn16);
        hipMemsetAsync(agg16, 0, (size_t)NNODES * NCLS * sizeof(float), stream);
        scatter16<<<NEDGE / 16, 256, 0, stream>>>(hn16, src + (size_t)r * NEDGE,
                                                  dst + (size_t)r * NEDGE, agg16);
        epi16<<<(NNODES * NCLS + 255) / 256, 256, 0, stream>>>(agg16, rs_in + (size_t)r * NNODES,
                                                               b2 + (size_t)r * NCLS, out);
    }
}

// Round 2
// 1949.715 us; speedup vs baseline: 1.4354x; 1.4354x over previous
//
#include <hip/hip_runtime.h>

// RGCN: 3× HeteroGraphConv(mean over R=4 relations of GraphConv(norm='both')).
// R1: replaced atomic edge-scatter (179us x8, atomic-RMW bound) with dst-CSR
// gather (no atomics, agg written once). CSR built once per call, shared by
// all layers. Layer 2: diag(rs)*(H@W) == (diag(rs)H)@W lets all 4 relations
// share ONE [N,128]@[128,64] GEMM; fused gather+epilogue writes out directly.

#define NNODES 100000
#define NEDGE  400000
#define NREL   4
#define DHID   128
#define NCLS   16
#define SCANB  98            // ceil(N / 1024)

// ---------------- int degree histograms ----------------
__global__ void edge_hist(const int* __restrict__ src, const int* __restrict__ dst,
                          int* __restrict__ cnt_out, int* __restrict__ cnt_in) {
    int e = blockIdx.x * 256 + threadIdx.x;
    int r = blockIdx.y;
    if (e < NEDGE) {
        atomicAdd(&cnt_out[r * NNODES + src[r * NEDGE + e]], 1);
        atomicAdd(&cnt_in [r * NNODES + dst[r * NEDGE + e]], 1);
    }
}

__global__ void rs_fin(const int* __restrict__ cnt_out, const int* __restrict__ cnt_in,
                       float* __restrict__ rs_out, float* __restrict__ rs_in) {
    int i = blockIdx.x * 256 + threadIdx.x;
    if (i < NREL * NNODES) {
        rs_out[i] = rsqrtf(fmaxf((float)cnt_out[i], 1.0f));
        rs_in [i] = rsqrtf(fmaxf((float)cnt_in [i], 1.0f));
    }
}

// ---------------- 2-level exclusive scan of cnt_in -> ofs ----------------
__global__ void scan1(const int* __restrict__ cnt, int* __restrict__ part) {
    __shared__ int sh[256];
    int r = blockIdx.y, b = blockIdx.x, tid = threadIdx.x;
    int n0 = b * 1024 + tid * 4;
    int s = 0;
#pragma unroll
    for (int j = 0; j < 4; ++j) {
        int n = n0 + j;
        s += (n < NNODES) ? cnt[r * NNODES + n] : 0;
    }
    sh[tid] = s; __syncthreads();
    for (int off = 128; off > 0; off >>= 1) {
        if (tid < off) sh[tid] += sh[tid + off];
        __syncthreads();
    }
    if (tid == 0) part[r * SCANB + b] = sh[0];
}

__global__ void scan2(int* __restrict__ part) {
    __shared__ int sh[128];
    int r = blockIdx.x, tid = threadIdx.x;
    int v = (tid < SCANB) ? part[r * SCANB + tid] : 0;
    sh[tid] = v; __syncthreads();
    for (int off = 1; off < 128; off <<= 1) {
        int t = (tid >= off) ? sh[tid - off] : 0;
        __syncthreads();
        sh[tid] += t;
        __syncthreads();
    }
    if (tid < SCANB) part[r * SCANB + tid] = sh[tid] - v;  // exclusive
}

__global__ void scan3(const int* __restrict__ cnt, const int* __restrict__ part,
                      int* __restrict__ ofs) {
    __shared__ int sh[256];
    int r = blockIdx.y, b = blockIdx.x, tid = threadIdx.x;
    int n0 = b * 1024 + tid * 4;
    int v[4];
    int tsum = 0;
#pragma unroll
    for (int j = 0; j < 4; ++j) {
        int n = n0 + j;
        v[j] = (n < NNODES) ? cnt[r * NNODES + n] : 0;
        tsum += v[j];
    }
    sh[tid] = tsum; __syncthreads();
    for (int off = 1; off < 256; off <<= 1) {
        int t = (tid >= off) ? sh[tid - off] : 0;
        __syncthreads();
        sh[tid] += t;
        __syncthreads();
    }
    int base = part[r * SCANB + b] + sh[tid] - tsum;   // exclusive for this thread
#pragma unroll
    for (int j = 0; j < 4; ++j) {
        int n = n0 + j;
        if (n < NNODES) ofs[r * (NNODES + 1) + n] = base;
        base += v[j];
    }
    if (b == 0 && tid == 0) ofs[r * (NNODES + 1) + NNODES] = NEDGE;
}

// fill CSR; consumes cnt_in as a countdown cursor (order within a segment is
// arbitrary — sum is order-independent up to fp rounding).
__global__ void csr_fill(const int* __restrict__ src, const int* __restrict__ dst,
                         const int* __restrict__ ofs, int* __restrict__ cnt_in,
                         int* __restrict__ csr) {
    int e = blockIdx.x * 256 + threadIdx.x;
    int r = blockIdx.y;
    if (e < NEDGE) {
        int s = src[r * NEDGE + e], d = dst[r * NEDGE + e];
        int k = atomicSub(&cnt_in[r * NNODES + d], 1) - 1;
        csr[(size_t)r * NEDGE + ofs[r * (NNODES + 1) + d] + k] = s;
    }
}

// ---------------- CSR gather, 128 feats: agg[d] = sum_in h[s]*rs_out[s] ----------------
__global__ void gather128(const float* __restrict__ h, const float* __restrict__ rs,
                          const int* __restrict__ ofs, const int* __restrict__ csr,
                          float* __restrict__ agg) {
    int d = blockIdx.x * 2 + (threadIdx.x >> 7);
    int j = threadIdx.x & 127;
    if (d >= NNODES) return;
    int i   = ofs[d];
    int end = ofs[d + 1];
    float acc = 0.f;
    for (; i < end; ++i) {
        int s = csr[i];
        acc += h[s * DHID + j] * rs[s];
    }
    agg[d * DHID + j] = acc;
}

// ---------------- GEMM 128x128 with fused GraphConv epilogue ----------------
// h[row,:] (+)= relu_opt((A[row,:] @ W) * rs_in[row] + bias) * (1/R)
template <int RELU, int INIT>
__global__ __launch_bounds__(256) void gemm128_ep(
        const float* __restrict__ A, const float* __restrict__ W,
        const float* __restrict__ bias, const float* __restrict__ rsin,
        float* __restrict__ out) {
    __shared__ float As[128][33];
    __shared__ float Ws[32][132];
    int tid = threadIdx.x;
    int tx = tid & 15;
    int ty = tid >> 4;
    int row0 = blockIdx.x * 128;

    float acc[8][8];
#pragma unroll
    for (int i = 0; i < 8; ++i)
#pragma unroll
        for (int j = 0; j < 8; ++j) acc[i][j] = 0.f;

    for (int kt = 0; kt < 4; ++kt) {
        int k0 = kt * 32;
#pragma unroll
        for (int i = 0; i < 16; ++i) {
            int idx = tid + i * 256;
            int rr = idx >> 5, kk = idx & 31;
            int row = row0 + rr;
            As[rr][kk] = (row < NNODES) ? A[row * DHID + k0 + kk] : 0.f;
        }
#pragma unroll
        for (int i = 0; i < 16; ++i) {
            int idx = tid + i * 256;
            int rr = idx >> 7, cc = idx & 127;
            Ws[rr][cc] = W[(k0 + rr) * DHID + cc];
        }
        __syncthreads();
#pragma unroll
        for (int k = 0; k < 32; ++k) {
            float a[8], w[8];
#pragma unroll
            for (int i = 0; i < 8; ++i) a[i] = As[ty * 8 + i][k];
#pragma unroll
            for (int j = 0; j < 8; ++j) w[j] = Ws[k][tx * 8 + j];
#pragma unroll
            for (int i = 0; i < 8; ++i)
#pragma unroll
                for (int j = 0; j < 8; ++j) acc[i][j] += a[i] * w[j];
        }
        __syncthreads();
    }

#pragma unroll
    for (int i = 0; i < 8; ++i) {
        int row = row0 + ty * 8 + i;
        if (row < NNODES) {
            float rs = rsin[row];
#pragma unroll
            for (int j = 0; j < 8; ++j) {
                int c = tx * 8 + j;
                float v = acc[i][j] * rs + bias[c];
                if (RELU) v = fmaxf(v, 0.f);
                if (INIT) out[row * DHID + c] = v * 0.25f;
                else      out[row * DHID + c] += v * 0.25f;
            }
        }
    }
}

// ---------------- layer 2: hw = H @ [W2_0|W2_1|W2_2|W2_3]   [N,128]@[128,64] ----------------
// rs_out row-scaling commutes through the matmul; applied in the gather instead.
__global__ __launch_bounds__(256) void gemm64(const float* __restrict__ H,
                                              const float* __restrict__ W2,
                                              float* __restrict__ hw) {
    __shared__ float As[64][68];
    __shared__ float Ws[64][68];
    int tid = threadIdx.x;
    int tx = tid & 15, ty = tid >> 4;
    int row0 = blockIdx.x * 64;
    float acc[4][4];
#pragma unroll
    for (int i = 0; i < 4; ++i)
#pragma unroll
        for (int j = 0; j < 4; ++j) acc[i][j] = 0.f;

    for (int kt = 0; kt < 2; ++kt) {
        int k0 = kt * 64;
#pragma unroll
        for (int i = 0; i < 16; ++i) {      // A tile 64x64
            int idx = tid + i * 256;
            int rr = idx >> 6, kk = idx & 63;
            int row = row0 + rr;
            As[rr][kk] = (row < NNODES) ? H[row * DHID + k0 + kk] : 0.f;
        }
#pragma unroll
        for (int i = 0; i < 16; ++i) {      // W tile 64x64: Wcat[k][r*16+c] = W2[r][k][c]
            int idx = tid + i * 256;
            int kk = idx >> 6, cc = idx & 63;
            int r = cc >> 4, c = cc & 15;
            Ws[kk][cc] = W2[r * (DHID * NCLS) + (k0 + kk) * NCLS + c];
        }
        __syncthreads();
#pragma unroll
        for (int k = 0; k < 64; ++k) {
            float a[4], w[4];
#pragma unroll
            for (int i = 0; i < 4; ++i) a[i] = As[ty * 4 + i][k];
#pragma unroll
            for (int j = 0; j < 4; ++j) w[j] = Ws[k][tx * 4 + j];
#pragma unroll
            for (int i = 0; i < 4; ++i)
#pragma unroll
                for (int j = 0; j < 4; ++j) acc[i][j] += a[i] * w[j];
        }
        __syncthreads();
    }
#pragma unroll
    for (int i = 0; i < 4; ++i) {
        int row = row0 + ty * 4 + i;
        if (row < NNODES)
#pragma unroll
            for (int j = 0; j < 4; ++j) hw[row * 64 + tx * 4 + j] = acc[i][j];
    }
}

// fused layer-2 gather + epilogue over all 4 relations; writes out once.
__global__ void l2_out(const float* __restrict__ hw, const int* __restrict__ ofs,
                       const int* __restrict__ csr, const float* __restrict__ rs_out,
                       const float* __restrict__ rs_in, const float* __restrict__ b2,
                       float* __restrict__ out) {
    int d = blockIdx.x * 16 + (threadIdx.x >> 4);
    int c = threadIdx.x & 15;
    if (d >= NNODES) return;
    float tot = 0.f;
#pragma unroll
    for (int r = 0; r < NREL; ++r) {
        int i   = ofs[r * (NNODES + 1) + d];
        int end = ofs[r * (NNODES + 1) + d + 1];
        const int* cs = csr + (size_t)r * NEDGE;
        float acc = 0.f;
        for (; i < end; ++i) {
            int s = cs[i];
            acc += hw[s * 64 + r * NCLS + c] * rs_out[r * NNODES + s];
        }
        tot += acc * rs_in[r * NNODES + d] + b2[r * NCLS + c];
    }
    out[d * NCLS + c] = tot * 0.25f;
}

extern "C" void kernel_launch(void* const* d_in, const int* in_sizes, int n_in,
                              void* d_out, int out_size, void* d_ws, size_t ws_size,
                              hipStream_t stream) {
    const float* x  = (const float*)d_in[0];
    const float* W0 = (const float*)d_in[1];
    const float* b0 = (const float*)d_in[2];
    const float* W1 = (const float*)d_in[3];
    const float* b1 = (const float*)d_in[4];
    const float* W2 = (const float*)d_in[5];
    const float* b2 = (const float*)d_in[6];
    const int*   src = (const int*)d_in[7];
    const int*   dst = (const int*)d_in[8];
    float* out = (float*)d_out;

    // ---- workspace layout ----
    char* p = (char*)d_ws;
    int* cnt_out = (int*)p;               p += sizeof(int) * NREL * NNODES;
    int* cnt_in  = (int*)p;               p += sizeof(int) * NREL * NNODES;
    int* ofs     = (int*)p;               p += sizeof(int) * NREL * (NNODES + 1);
    int* part    = (int*)p;               p += sizeof(int) * NREL * 128;
    int* csr     = (int*)p;               p += sizeof(int) * (size_t)NREL * NEDGE;
    float* rs_out = (float*)p;            p += sizeof(float) * NREL * NNODES;
    float* rs_in  = (float*)p;            p += sizeof(float) * NREL * NNODES;
    float* h1     = (float*)p;            p += sizeof(float) * (size_t)NNODES * DHID;
    float* h2     = (float*)p;            p += sizeof(float) * (size_t)NNODES * DHID;
    float* agg    = (float*)p;            p += sizeof(float) * (size_t)NNODES * DHID;
    float* hw     = h1;                   // layer-2 reuse (needs N*64 <= N*128)

    // ---- CSR + norms (once; graph shared by all 3 layers) ----
    hipMemsetAsync(cnt_out, 0, 2ull * NREL * NNODES * sizeof(int), stream);
    dim3 eg((NEDGE + 255) / 256, NREL);
    edge_hist<<<eg, 256, 0, stream>>>(src, dst, cnt_out, cnt_in);
    rs_fin<<<(NREL * NNODES + 255) / 256, 256, 0, stream>>>(cnt_out, cnt_in, rs_out, rs_in);
    dim3 sg(SCANB, NREL);
    scan1<<<sg, 256, 0, stream>>>(cnt_in, part);
    scan2<<<NREL, 128, 0, stream>>>(part);
    scan3<<<sg, 256, 0, stream>>>(cnt_in, part, ofs);
    csr_fill<<<eg, 256, 0, stream>>>(src, dst, ofs, cnt_in, csr);

    int gemm_blocks = (NNODES + 127) / 128;

    // ---- layer 0: x -> h1 (relu) ----
    for (int r = 0; r < NREL; ++r) {
        gather128<<<NNODES / 2, 256, 0, stream>>>(x, rs_out + (size_t)r * NNODES,
                                                  ofs + r * (NNODES + 1),
                                                  csr + (size_t)r * NEDGE, agg);
        if (r == 0)
            gemm128_ep<1, 1><<<gemm_blocks, 256, 0, stream>>>(agg, W0 + (size_t)r * DHID * DHID,
                                                              b0 + (size_t)r * DHID,
                                                              rs_in + (size_t)r * NNODES, h1);
        else
            gemm128_ep<1, 0><<<gemm_blocks, 256, 0, stream>>>(agg, W0 + (size_t)r * DHID * DHID,
                                                              b0 + (size_t)r * DHID,
                                                              rs_in + (size_t)r * NNODES, h1);
    }

    // ---- layer 1: h1 -> h2 (relu) ----
    for (int r = 0; r < NREL; ++r) {
        gather128<<<NNODES / 2, 256, 0, stream>>>(h1, rs_out + (size_t)r * NNODES,
                                                  ofs + r * (NNODES + 1),
                                                  csr + (size_t)r * NEDGE, agg);
        if (r == 0)
            gemm128_ep<1, 1><<<gemm_blocks, 256, 0, stream>>>(agg, W1 + (size_t)r * DHID * DHID,
                                                              b1 + (size_t)r * DHID,
                                                              rs_in + (size_t)r * NNODES, h2);
        else
            gemm128_ep<1, 0><<<gemm_blocks, 256, 0, stream>>>(agg, W1 + (size_t)r * DHID * DHID,
                                                              b1 + (size_t)r * DHID,
                                                              rs_in + (size_t)r * NNODES, h2);
    }

    // ---- layer 2: one GEMM (all relations), fused gather+epilogue ----
    gemm64<<<(NNODES + 63) / 64, 256, 0, stream>>>(h2, W2, hw);
    l2_out<<<(NNODES + 15) / 16, 256, 0, stream>>>(hw, ofs, csr, rs_out, rs_in, b2, out);
}

// Round 3
// 1219.236 us; speedup vs baseline: 2.2953x; 1.5991x over previous
//
#include <hip/hip_runtime.h>

// RGCN: 3× HeteroGraphConv(mean over R=4 relations of GraphConv(norm='both')).
// R2: layers 0/1 GEMMs moved from fp32 VALU to split-precision fp16x2 MFMA
// (A=hi+lo fp16 planes written by gather; W pre-split into frag layout; 3
// mfma_f32_16x16x32_f16 per product -> ~1e-5 rel err). Gather degree loop
// unrolled x4 for L3-latency hiding. CSR build unchanged (edge_hist 124us =
// next target).

#define NNODES 100000
#define NEDGE  400000
#define NREL   4
#define DHID   128
#define NCLS   16
#define SCANB  98            // ceil(N / 1024)

typedef _Float16 f16x8 __attribute__((ext_vector_type(8)));
typedef float    f32x4 __attribute__((ext_vector_type(4)));

// ---------------- int degree histograms ----------------
__global__ void edge_hist(const int* __restrict__ src, const int* __restrict__ dst,
                          int* __restrict__ cnt_out, int* __restrict__ cnt_in) {
    int e = blockIdx.x * 256 + threadIdx.x;
    int r = blockIdx.y;
    if (e < NEDGE) {
        atomicAdd(&cnt_out[r * NNODES + src[r * NEDGE + e]], 1);
        atomicAdd(&cnt_in [r * NNODES + dst[r * NEDGE + e]], 1);
    }
}

__global__ void rs_fin(const int* __restrict__ cnt_out, const int* __restrict__ cnt_in,
                       float* __restrict__ rs_out, float* __restrict__ rs_in) {
    int i = blockIdx.x * 256 + threadIdx.x;
    if (i < NREL * NNODES) {
        rs_out[i] = rsqrtf(fmaxf((float)cnt_out[i], 1.0f));
        rs_in [i] = rsqrtf(fmaxf((float)cnt_in [i], 1.0f));
    }
}

// ---------------- 2-level exclusive scan of cnt_in -> ofs ----------------
__global__ void scan1(const int* __restrict__ cnt, int* __restrict__ part) {
    __shared__ int sh[256];
    int r = blockIdx.y, b = blockIdx.x, tid = threadIdx.x;
    int n0 = b * 1024 + tid * 4;
    int s = 0;
#pragma unroll
    for (int j = 0; j < 4; ++j) {
        int n = n0 + j;
        s += (n < NNODES) ? cnt[r * NNODES + n] : 0;
    }
    sh[tid] = s; __syncthreads();
    for (int off = 128; off > 0; off >>= 1) {
        if (tid < off) sh[tid] += sh[tid + off];
        __syncthreads();
    }
    if (tid == 0) part[r * SCANB + b] = sh[0];
}

__global__ void scan2(int* __restrict__ part) {
    __shared__ int sh[128];
    int r = blockIdx.x, tid = threadIdx.x;
    int v = (tid < SCANB) ? part[r * SCANB + tid] : 0;
    sh[tid] = v; __syncthreads();
    for (int off = 1; off < 128; off <<= 1) {
        int t = (tid >= off) ? sh[tid - off] : 0;
        __syncthreads();
        sh[tid] += t;
        __syncthreads();
    }
    if (tid < SCANB) part[r * SCANB + tid] = sh[tid] - v;  // exclusive
}

__global__ void scan3(const int* __restrict__ cnt, const int* __restrict__ part,
                      int* __restrict__ ofs) {
    __shared__ int sh[256];
    int r = blockIdx.y, b = blockIdx.x, tid = threadIdx.x;
    int n0 = b * 1024 + tid * 4;
    int v[4];
    int tsum = 0;
#pragma unroll
    for (int j = 0; j < 4; ++j) {
        int n = n0 + j;
        v[j] = (n < NNODES) ? cnt[r * NNODES + n] : 0;
        tsum += v[j];
    }
    sh[tid] = tsum; __syncthreads();
    for (int off = 1; off < 256; off <<= 1) {
        int t = (tid >= off) ? sh[tid - off] : 0;
        __syncthreads();
        sh[tid] += t;
        __syncthreads();
    }
    int base = part[r * SCANB + b] + sh[tid] - tsum;
#pragma unroll
    for (int j = 0; j < 4; ++j) {
        int n = n0 + j;
        if (n < NNODES) ofs[r * (NNODES + 1) + n] = base;
        base += v[j];
    }
    if (b == 0 && tid == 0) ofs[r * (NNODES + 1) + NNODES] = NEDGE;
}

__global__ void csr_fill(const int* __restrict__ src, const int* __restrict__ dst,
                         const int* __restrict__ ofs, int* __restrict__ cnt_in,
                         int* __restrict__ csr) {
    int e = blockIdx.x * 256 + threadIdx.x;
    int r = blockIdx.y;
    if (e < NEDGE) {
        int s = src[r * NEDGE + e], d = dst[r * NEDGE + e];
        int k = atomicSub(&cnt_in[r * NNODES + d], 1) - 1;
        csr[(size_t)r * NEDGE + ofs[r * (NNODES + 1) + d] + k] = s;
    }
}

// ---------------- W pre-split into MFMA frag layout ----------------
// Wt[r][kt][kb][c][j] (halves), k = kt*32 + kb*8 + j.  Per W: 4*128*128 elems.
__global__ void wsplit(const float* __restrict__ W, _Float16* __restrict__ whi,
                       _Float16* __restrict__ wlo) {
    int idx = blockIdx.x * 256 + threadIdx.x;   // 4*128*128 = 65536
    int c = idx & 127, k = (idx >> 7) & 127, r = idx >> 14;
    float w = W[(size_t)r * 16384 + k * 128 + c];
    _Float16 hi = (_Float16)w;
    int kt = k >> 5, kb = (k >> 3) & 3, jj = k & 7;
    size_t o = (((size_t)r * 16 + kt * 4 + kb) * 128 + c) * 8 + jj;
    whi[o] = hi;
    wlo[o] = (_Float16)(w - (float)hi);
}

// ---------------- CSR gather -> split fp16 planes ----------------
__global__ void gather128(const float* __restrict__ h, const float* __restrict__ rs,
                          const int* __restrict__ ofs, const int* __restrict__ csr,
                          _Float16* __restrict__ ahi, _Float16* __restrict__ alo) {
    int d = blockIdx.x * 2 + (threadIdx.x >> 7);
    int j = threadIdx.x & 127;
    int i   = ofs[d];
    int end = ofs[d + 1];
    float acc = 0.f;
    for (; i + 4 <= end; i += 4) {          // 4 concurrent L3 row loads
        int s0 = csr[i], s1 = csr[i + 1], s2 = csr[i + 2], s3 = csr[i + 3];
        float v0 = h[(size_t)s0 * DHID + j] * rs[s0];
        float v1 = h[(size_t)s1 * DHID + j] * rs[s1];
        float v2 = h[(size_t)s2 * DHID + j] * rs[s2];
        float v3 = h[(size_t)s3 * DHID + j] * rs[s3];
        acc += (v0 + v1) + (v2 + v3);
    }
    for (; i < end; ++i) {
        int s = csr[i];
        acc += h[(size_t)s * DHID + j] * rs[s];
    }
    _Float16 hi = (_Float16)acc;
    ahi[(size_t)d * DHID + j] = hi;
    alo[(size_t)d * DHID + j] = (_Float16)(acc - (float)hi);
}

// ---------------- MFMA GEMM [N,128]@[128,128] + fused epilogue ----------------
// out[row,:] (+)= relu((A@W)*rs_in[row] + bias) * 0.25, A = ahi+alo, W = whi+wlo.
template <int INIT>
__global__ __launch_bounds__(256) void gemm_l(
        const _Float16* __restrict__ Ahi, const _Float16* __restrict__ Alo,
        const _Float16* __restrict__ Whi, const _Float16* __restrict__ Wlo,
        const float* __restrict__ bias, const float* __restrict__ rsin,
        float* __restrict__ out) {
    __shared__ _Float16 lhi[4 * 130 * 8];
    __shared__ _Float16 llo[4 * 130 * 8];
    int tid = threadIdx.x;
    int lane = tid & 63, wid = tid >> 6;
    int wm = wid >> 1, wn = wid & 1;        // 2x2 waves, 64x64 each
    int row0 = blockIdx.x * 128;

    f32x4 acc[4][4] = {};                   // [mf][nf]

    for (int kt = 0; kt < 4; ++kt) {
        // W frags direct from global (L2-hot, frag-layout, coalesced)
        f16x8 wf_hi[4], wf_lo[4];
        {
            int c  = wn * 64 + (lane & 15);
            int kb = lane >> 4;
            const _Float16* bh = Whi + ((size_t)(kt * 4 + kb) * 128) * 8;
            const _Float16* bl = Wlo + ((size_t)(kt * 4 + kb) * 128) * 8;
#pragma unroll
            for (int nf = 0; nf < 4; ++nf) {
                wf_hi[nf] = *(const f16x8*)(bh + (size_t)(c + nf * 16) * 8);
                wf_lo[nf] = *(const f16x8*)(bl + (size_t)(c + nf * 16) * 8);
            }
        }
        __syncthreads();                    // LDS safe to overwrite
        int k0 = kt * 32;
#pragma unroll
        for (int it = 0; it < 2; ++it) {    // stage A tile 128x32, both planes
            int idx = tid + it * 256;
            int row = idx >> 2, kb = idx & 3;
            int grow = row0 + row;
            f16x8 vh = {}, vl = {};
            if (grow < NNODES) {
                vh = *(const f16x8*)&Ahi[(size_t)grow * DHID + k0 + kb * 8];
                vl = *(const f16x8*)&Alo[(size_t)grow * DHID + k0 + kb * 8];
            }
            *(f16x8*)&lhi[(kb * 130 + row) * 8] = vh;
            *(f16x8*)&llo[(kb * 130 + row) * 8] = vl;
        }
        __syncthreads();

        f16x8 af_hi[4], af_lo[4];
        int kb = lane >> 4, rbase = wm * 64 + (lane & 15);
#pragma unroll
        for (int mf = 0; mf < 4; ++mf) {
            af_hi[mf] = *(const f16x8*)&lhi[(kb * 130 + rbase + mf * 16) * 8];
            af_lo[mf] = *(const f16x8*)&llo[(kb * 130 + rbase + mf * 16) * 8];
        }
#pragma unroll
        for (int nf = 0; nf < 4; ++nf)
#pragma unroll
            for (int mf = 0; mf < 4; ++mf) {
                acc[mf][nf] = __builtin_amdgcn_mfma_f32_16x16x32_f16(af_hi[mf], wf_hi[nf], acc[mf][nf], 0, 0, 0);
                acc[mf][nf] = __builtin_amdgcn_mfma_f32_16x16x32_f16(af_hi[mf], wf_lo[nf], acc[mf][nf], 0, 0, 0);
                acc[mf][nf] = __builtin_amdgcn_mfma_f32_16x16x32_f16(af_lo[mf], wf_hi[nf], acc[mf][nf], 0, 0, 0);
            }
    }

    // epilogue: C/D layout col=lane&15, row=(lane>>4)*4+i
    int rsub = (lane >> 4) * 4;
#pragma unroll
    for (int mf = 0; mf < 4; ++mf) {
#pragma unroll
        for (int i = 0; i < 4; ++i) {
            int rr = row0 + wm * 64 + mf * 16 + rsub + i;
            if (rr < NNODES) {
                float rs = rsin[rr];
#pragma unroll
                for (int nf = 0; nf < 4; ++nf) {
                    int c = wn * 64 + nf * 16 + (lane & 15);
                    float v = acc[mf][nf][i] * rs + bias[c];
                    v = fmaxf(v, 0.f);
                    if (INIT) out[(size_t)rr * DHID + c] = v * 0.25f;
                    else      out[(size_t)rr * DHID + c] += v * 0.25f;
                }
            }
        }
    }
}

// ---------------- layer 2 (fp32, small): hw = H @ [W2_0|..|W2_3] ----------------
__global__ __launch_bounds__(256) void gemm64(const float* __restrict__ H,
                                              const float* __restrict__ W2,
                                              float* __restrict__ hw) {
    __shared__ float As[64][68];
    __shared__ float Ws[64][68];
    int tid = threadIdx.x;
    int tx = tid & 15, ty = tid >> 4;
    int row0 = blockIdx.x * 64;
    float acc[4][4];
#pragma unroll
    for (int i = 0; i < 4; ++i)
#pragma unroll
        for (int j = 0; j < 4; ++j) acc[i][j] = 0.f;

    for (int kt = 0; kt < 2; ++kt) {
        int k0 = kt * 64;
#pragma unroll
        for (int i = 0; i < 16; ++i) {
            int idx = tid + i * 256;
            int rr = idx >> 6, kk = idx & 63;
            int row = row0 + rr;
            As[rr][kk] = (row < NNODES) ? H[(size_t)row * DHID + k0 + kk] : 0.f;
        }
#pragma unroll
        for (int i = 0; i < 16; ++i) {
            int idx = tid + i * 256;
            int kk = idx >> 6, cc = idx & 63;
            int r = cc >> 4, c = cc & 15;
            Ws[kk][cc] = W2[r * (DHID * NCLS) + (k0 + kk) * NCLS + c];
        }
        __syncthreads();
#pragma unroll
        for (int k = 0; k < 64; ++k) {
            float a[4], w[4];
#pragma unroll
            for (int i = 0; i < 4; ++i) a[i] = As[ty * 4 + i][k];
#pragma unroll
            for (int j = 0; j < 4; ++j) w[j] = Ws[k][tx * 4 + j];
#pragma unroll
            for (int i = 0; i < 4; ++i)
#pragma unroll
                for (int j = 0; j < 4; ++j) acc[i][j] += a[i] * w[j];
        }
        __syncthreads();
    }
#pragma unroll
    for (int i = 0; i < 4; ++i) {
        int row = row0 + ty * 4 + i;
        if (row < NNODES)
#pragma unroll
            for (int j = 0; j < 4; ++j) hw[(size_t)row * 64 + tx * 4 + j] = acc[i][j];
    }
}

__global__ void l2_out(const float* __restrict__ hw, const int* __restrict__ ofs,
                       const int* __restrict__ csr, const float* __restrict__ rs_out,
                       const float* __restrict__ rs_in, const float* __restrict__ b2,
                       float* __restrict__ out) {
    int d = blockIdx.x * 16 + (threadIdx.x >> 4);
    int c = threadIdx.x & 15;
    if (d >= NNODES) return;
    float tot = 0.f;
#pragma unroll
    for (int r = 0; r < NREL; ++r) {
        int i   = ofs[r * (NNODES + 1) + d];
        int end = ofs[r * (NNODES + 1) + d + 1];
        const int* cs = csr + (size_t)r * NEDGE;
        float acc = 0.f;
        for (; i + 2 <= end; i += 2) {
            int s0 = cs[i], s1 = cs[i + 1];
            acc += hw[(size_t)s0 * 64 + r * NCLS + c] * rs_out[r * NNODES + s0]
                 + hw[(size_t)s1 * 64 + r * NCLS + c] * rs_out[r * NNODES + s1];
        }
        for (; i < end; ++i) {
            int s = cs[i];
            acc += hw[(size_t)s * 64 + r * NCLS + c] * rs_out[r * NNODES + s];
        }
        tot += acc * rs_in[r * NNODES + d] + b2[r * NCLS + c];
    }
    out[(size_t)d * NCLS + c] = tot * 0.25f;
}

extern "C" void kernel_launch(void* const* d_in, const int* in_sizes, int n_in,
                              void* d_out, int out_size, void* d_ws, size_t ws_size,
                              hipStream_t stream) {
    const float* x  = (const float*)d_in[0];
    const float* W0 = (const float*)d_in[1];
    const float* b0 = (const float*)d_in[2];
    const float* W1 = (const float*)d_in[3];
    const float* b1 = (const float*)d_in[4];
    const float* W2 = (const float*)d_in[5];
    const float* b2 = (const float*)d_in[6];
    const int*   src = (const int*)d_in[7];
    const int*   dst = (const int*)d_in[8];
    float* out = (float*)d_out;

    // ---- workspace layout (~167 MB) ----
    char* p = (char*)d_ws;
    int* cnt_out = (int*)p;            p += sizeof(int) * NREL * NNODES;
    int* cnt_in  = (int*)p;            p += sizeof(int) * NREL * NNODES;
    int* ofs     = (int*)p;            p += sizeof(int) * NREL * (NNODES + 1) + 12; // pad to 16B
    int* part    = (int*)p;            p += sizeof(int) * NREL * 128;
    int* csr     = (int*)p;            p += sizeof(int) * (size_t)NREL * NEDGE;
    float* rs_out = (float*)p;         p += sizeof(float) * NREL * NNODES;
    float* rs_in  = (float*)p;         p += sizeof(float) * NREL * NNODES;
    _Float16* Wt0h = (_Float16*)p;     p += sizeof(_Float16) * NREL * DHID * DHID;
    _Float16* Wt0l = (_Float16*)p;     p += sizeof(_Float16) * NREL * DHID * DHID;
    _Float16* Wt1h = (_Float16*)p;     p += sizeof(_Float16) * NREL * DHID * DHID;
    _Float16* Wt1l = (_Float16*)p;     p += sizeof(_Float16) * NREL * DHID * DHID;
    _Float16* Ahi  = (_Float16*)p;     p += sizeof(_Float16) * (size_t)NNODES * DHID;
    _Float16* Alo  = (_Float16*)p;     p += sizeof(_Float16) * (size_t)NNODES * DHID;
    float* h1     = (float*)p;         p += sizeof(float) * (size_t)NNODES * DHID;
    float* h2     = (float*)p;         p += sizeof(float) * (size_t)NNODES * DHID;
    float* hw     = h1;                // layer-2 reuse

    // ---- CSR + norms (once; shared by all layers) ----
    hipMemsetAsync(cnt_out, 0, 2ull * NREL * NNODES * sizeof(int), stream);
    dim3 eg((NEDGE + 255) / 256, NREL);
    edge_hist<<<eg, 256, 0, stream>>>(src, dst, cnt_out, cnt_in);
    rs_fin<<<(NREL * NNODES + 255) / 256, 256, 0, stream>>>(cnt_out, cnt_in, rs_out, rs_in);
    dim3 sg(SCANB, NREL);
    scan1<<<sg, 256, 0, stream>>>(cnt_in, part);
    scan2<<<NREL, 128, 0, stream>>>(part);
    scan3<<<sg, 256, 0, stream>>>(cnt_in, part, ofs);
    csr_fill<<<eg, 256, 0, stream>>>(src, dst, ofs, cnt_in, csr);

    // ---- W splits (frag layout) ----
    wsplit<<<256, 256, 0, stream>>>(W0, Wt0h, Wt0l);
    wsplit<<<256, 256, 0, stream>>>(W1, Wt1h, Wt1l);

    int gb = (NNODES + 127) / 128;

    // ---- layer 0: x -> h1 ----
    for (int r = 0; r < NREL; ++r) {
        gather128<<<NNODES / 2, 256, 0, stream>>>(x, rs_out + (size_t)r * NNODES,
                                                  ofs + r * (NNODES + 1),
                                                  csr + (size_t)r * NEDGE, Ahi, Alo);
        size_t wo = (size_t)r * DHID * DHID;
        if (r == 0)
            gemm_l<1><<<gb, 256, 0, stream>>>(Ahi, Alo, Wt0h + wo, Wt0l + wo,
                                              b0 + r * DHID, rs_in + (size_t)r * NNODES, h1);
        else
            gemm_l<0><<<gb, 256, 0, stream>>>(Ahi, Alo, Wt0h + wo, Wt0l + wo,
                                              b0 + r * DHID, rs_in + (size_t)r * NNODES, h1);
    }

    // ---- layer 1: h1 -> h2 ----
    for (int r = 0; r < NREL; ++r) {
        gather128<<<NNODES / 2, 256, 0, stream>>>(h1, rs_out + (size_t)r * NNODES,
                                                  ofs + r * (NNODES + 1),
                                                  csr + (size_t)r * NEDGE, Ahi, Alo);
        size_t wo = (size_t)r * DHID * DHID;
        if (r == 0)
            gemm_l<1><<<gb, 256, 0, stream>>>(Ahi, Alo, Wt1h + wo, Wt1l + wo,
                                              b1 + r * DHID, rs_in + (size_t)r * NNODES, h2);
        else
            gemm_l<0><<<gb, 256, 0, stream>>>(Ahi, Alo, Wt1h + wo, Wt1l + wo,
                                              b1 + r * DHID, rs_in + (size_t)r * NNODES, h2);
    }

    // ---- layer 2 ----
    gemm64<<<(NNODES + 63) / 64, 256, 0, stream>>>(h2, W2, hw);
    l2_out<<<(NNODES + 15) / 16, 256, 0, stream>>>(hw, ofs, csr, rs_out, rs_in, b2, out);
}